// Round 13
// baseline (286.694 us; speedup 1.0000x reference)
//
#include <hip/hip_runtime.h>
#include <hip/hip_bf16.h>
#include <hip/hip_fp16.h>
#include <math.h>

#define NN 100000
#define EE 1600000
#define HD_ 128   // heads*hid = 4*32
#define PART 8            // dst-range groups (XCD count)
#define RNG 12500         // NN / PART
#define PBLK 512          // blocks per group
#define SCATB (PART * PBLK)          // 4096 scatter blocks
#define PSTRIDE (PBLK * 256)
#define CAP 64            // bucket capacity per node (max deg ~42 whp)

typedef float f32x4 __attribute__((ext_vector_type(4)));
typedef _Float16 f16x8 __attribute__((ext_vector_type(8)));
typedef _Float16 f16x2 __attribute__((ext_vector_type(2)));
typedef float accf4 __attribute__((ext_vector_type(4)));

// ---------------------------------------------------------------------------
// fast tanh via hardware exp, overflow-safe form
// ---------------------------------------------------------------------------
__device__ __forceinline__ float fast_tanh(float z) {
    float az = fabsf(z);
    float e = __expf(-2.f * az);
    float t = (1.f - e) / (1.f + e);
    return copysignf(t, z);
}

struct alignas(16) h8 { __half2 h[4]; };  // 8 halves = 16B
struct alignas(8)  h4 { __half2 a, b; };  // 4 halves = 8B

// ---------------------------------------------------------------------------
// Kernel 0: one-time W transpose/convert into MFMA A-fragment layout (fp16).
// Frag index: (((mat*8 + ct)*4 + kt)*64 + lane)*8 + j
//   element = W_mat[kt*32 + (lane>>4)*8 + j][ct*16 + (lane&15)]
// ---------------------------------------------------------------------------
__global__ __launch_bounds__(256) void wt_kernel(
    const float* __restrict__ Wq, const float* __restrict__ Wk,
    const float* __restrict__ Wv, const float* __restrict__ Ws,
    __half* __restrict__ Wt)
{
    const int t = blockIdx.x * 256 + threadIdx.x;   // 0..8191
    const int lane = t & 63;
    const int kt = (t >> 6) & 3;
    const int ct = (t >> 8) & 7;
    const int mat = t >> 11;
    const float* Wm = (mat == 0) ? Wq : (mat == 1) ? Wk : (mat == 2) ? Wv : Ws;
    const int col = ct * 16 + (lane & 15);
    const int k0 = kt * 32 + (lane >> 4) * 8;
    h8 hh;
#pragma unroll
    for (int j = 0; j < 4; ++j) {
        hh.h[j] = __floats2half2_rn(Wm[(size_t)(k0 + 2 * j) * 128 + col],
                                    Wm[(size_t)(k0 + 2 * j + 1) * 128 + col]);
    }
    *reinterpret_cast<h8*>(Wt + (size_t)t * 8) = hh;
}

// ---------------------------------------------------------------------------
// Kernel 1: fused projections via MFMA, 512 threads / 32 nodes / 8 waves.
// Wave wid: matrix = wid&3 (0:Q,1:K,2:V,3:S), node half = (wid>>2)*16.
// Deeper per-block pipeline + halved block count vs the 256-thread version
// (which was latency-bound: VALUBusy 8%, MfmaUtil 3.5%, nothing saturated).
// ---------------------------------------------------------------------------
__global__ __launch_bounds__(512) void proj_mfma(
    const float* __restrict__ x, const __half* __restrict__ Wt,
    const float* __restrict__ bq, const float* __restrict__ bk,
    const float* __restrict__ bv, const float* __restrict__ bs,
    __half* __restrict__ Qh, __half* __restrict__ Sh, __half* __restrict__ KV)
{
    __shared__ __half xs[32][136];   // x tile fp16, padded stride
    __shared__ __half ys[32][520];   // output staging [node][mat*128+col]
    const int tid = threadIdx.x;
    const int n0 = blockIdx.x * 32;

    // stage x[32][128] -> fp16 LDS
    {
        const int row = tid & 31;
        const int k0 = (tid >> 5) * 8;   // 0..120
        const f32x4* xp = reinterpret_cast<const f32x4*>(
            x + (size_t)(n0 + row) * 128 + k0);
        f32x4 a = __builtin_nontemporal_load(xp);
        f32x4 b = __builtin_nontemporal_load(xp + 1);
        h8 hh;
        hh.h[0] = __floats2half2_rn(a.x, a.y);
        hh.h[1] = __floats2half2_rn(a.z, a.w);
        hh.h[2] = __floats2half2_rn(b.x, b.y);
        hh.h[3] = __floats2half2_rn(b.z, b.w);
        *reinterpret_cast<h8*>(&xs[row][k0]) = hh;
    }
    __syncthreads();

    const int wid = tid >> 6;       // 0..7
    const int lane = tid & 63;
    const int w = wid & 3;          // matrix
    const int nh = (wid >> 2) * 16; // node-half offset
    const float* bm = (w == 0) ? bq : (w == 1) ? bk : (w == 2) ? bv : bs;
    const float sc = (w == 0) ? 0.17677669529663687f : 1.f;  // 1/sqrt(32)

    f16x8 bx[4];
#pragma unroll
    for (int kt = 0; kt < 4; ++kt)
        bx[kt] = *reinterpret_cast<const f16x8*>(
            &xs[nh + (lane & 15)][kt * 32 + (lane >> 4) * 8]);

    const __half* wbase = Wt + (size_t)w * 16384;

#pragma unroll
    for (int ct = 0; ct < 8; ++ct) {
        accf4 acc = {0.f, 0.f, 0.f, 0.f};
#pragma unroll
        for (int kt = 0; kt < 4; ++kt) {
            f16x8 af = *reinterpret_cast<const f16x8*>(
                wbase + (size_t)((ct * 4 + kt) * 64 + lane) * 8);
            acc = __builtin_amdgcn_mfma_f32_16x16x32_f16(af, bx[kt], acc, 0, 0, 0);
        }
        const float4 bb = *reinterpret_cast<const float4*>(
            bm + ct * 16 + ((lane >> 4) << 2));
        h4 o;
        o.a = __floats2half2_rn((acc[0] + bb.x) * sc, (acc[1] + bb.y) * sc);
        o.b = __floats2half2_rn((acc[2] + bb.z) * sc, (acc[3] + bb.w) * sc);
        *reinterpret_cast<h4*>(
            &ys[nh + (lane & 15)][w * 128 + ct * 16 + ((lane >> 4) << 2)]) = o;
    }
    __syncthreads();

    // write out contiguous fp16 rows (512 threads cover 32 nodes x 16 chunks)
    {
        const int node = tid >> 4;       // 0..31
        const int c8 = (tid & 15) * 8;
        h8 q = *reinterpret_cast<h8*>(&ys[node][c8]);
        h8 k = *reinterpret_cast<h8*>(&ys[node][128 + c8]);
        h8 v = *reinterpret_cast<h8*>(&ys[node][256 + c8]);
        h8 s = *reinterpret_cast<h8*>(&ys[node][384 + c8]);
        *reinterpret_cast<h8*>(Qh + (size_t)(n0 + node) * 128 + c8) = q;
        *reinterpret_cast<h8*>(KV + (size_t)(n0 + node) * 256 + c8) = k;
        *reinterpret_cast<h8*>(KV + (size_t)(n0 + node) * 256 + 128 + c8) = v;
        *reinterpret_cast<h8*>(Sh + (size_t)(n0 + node) * 128 + c8) = s;
    }
}

// ---------------------------------------------------------------------------
// Kernel 2: single-pass bucket scatter. 8-way dst-range partition (each cnt
// line and node bucket written by one XCD group). 4096 blocks -> ~13
// dependent {load, atomic, store} iterations per thread (was 49).
// ---------------------------------------------------------------------------
__global__ __launch_bounds__(256) void bucket_scatter(
    const int* __restrict__ ei, int* __restrict__ cnt, int* __restrict__ ssrc)
{
    const int g = blockIdx.x & (PART - 1);
    const int bg = blockIdx.x >> 3;
    const int lo = g * RNG;
    const int hi = lo + RNG;
    for (int e = bg * 256 + threadIdx.x; e < EE; e += PSTRIDE) {
        const int d = ei[EE + e];
        if (d >= lo && d < hi) {
            int pos = atomicAdd(&cnt[d], 1);
            if (pos < CAP) ssrc[(d << 6) | pos] = ei[e];
        }
    }
}

// ---------------------------------------------------------------------------
// Kernel 3: per-node attention (no-max softmax) + skip + tanh -> h (fp16).
// One wave per node, NO LDS. 16 edges/iteration in four 4-edge batches.
// ---------------------------------------------------------------------------
__global__ __launch_bounds__(256) void attn_kernel(
    const __half* __restrict__ Qh, const __half* __restrict__ KV,
    const __half* __restrict__ Sh,
    const int* __restrict__ cnt, const int* __restrict__ ssrc,
    __half* __restrict__ hbuf)
{
    const int wid = threadIdx.x >> 6;
    const int lane = threadIdx.x & 63;
    const int node = blockIdx.x * 4 + wid;
    const int eg = lane >> 4;   // edge slot
    const int li = lane & 15;   // position within row

    // q dims 8*li..8*li+7, kept packed fp16 (pre-scaled by 1/sqrt(32))
    h8 qq = *reinterpret_cast<const h8*>(Qh + (size_t)node * 128 + li * 8);
    f16x2 qp[4];
#pragma unroll
    for (int j = 0; j < 4; ++j)
        qp[j] = *reinterpret_cast<const f16x2*>(&qq.h[j]);

    float a[8];
#pragma unroll
    for (int j = 0; j < 8; ++j) a[j] = 0.f;
    float l = 0.f;

    const int st = node << 6;
    int dg = cnt[node];
    if (dg > CAP) dg = CAP;

    for (int it = 0; it < dg; it += 16) {
        const __half* rows[4];
        bool val[4];
#pragma unroll
        for (int b = 0; b < 4; ++b) {
            const int e = it + b * 4 + eg;
            val[b] = e < dg;
            const int src = ssrc[st + (val[b] ? e : 0)];
            rows[b] = KV + (size_t)src * 256 + li * 8;
        }

        h8 kk[4], vv[4];
#pragma unroll
        for (int b = 0; b < 4; ++b) {
            kk[b] = *reinterpret_cast<const h8*>(rows[b]);
            vv[b] = *reinterpret_cast<const h8*>(rows[b] + 128);
        }

        float p[4];
#pragma unroll
        for (int b = 0; b < 4; ++b) {
            float s = 0.f;
#if __has_builtin(__builtin_amdgcn_fdot2)
#pragma unroll
            for (int j = 0; j < 4; ++j)
                s = __builtin_amdgcn_fdot2(
                        qp[j], *reinterpret_cast<const f16x2*>(&kk[b].h[j]),
                        s, false);
#else
#pragma unroll
            for (int j = 0; j < 4; ++j) {
                const float2 kf = __half22float2(kk[b].h[j]);
                const float2 qf = __half22float2(qq.h[j]);
                s = fmaf(qf.x, kf.x, s);
                s = fmaf(qf.y, kf.y, s);
            }
#endif
            p[b] = s;
        }

#pragma unroll
        for (int b = 0; b < 4; ++b) {
            p[b] += __shfl_xor(p[b], 1);
            p[b] += __shfl_xor(p[b], 2);
        }

        float w[4];
#pragma unroll
        for (int b = 0; b < 4; ++b) {
            w[b] = val[b] ? __expf(p[b]) : 0.f;
            l += w[b];
        }

#pragma unroll
        for (int b = 0; b < 4; ++b) {
#pragma unroll
            for (int j = 0; j < 4; ++j) {
                const float2 vf = __half22float2(vv[b].h[j]);
                a[2 * j]     = fmaf(w[b], vf.x, a[2 * j]);
                a[2 * j + 1] = fmaf(w[b], vf.y, a[2 * j + 1]);
            }
        }
    }

    // combine the 4 edge slots
#pragma unroll
    for (int j = 0; j < 8; ++j) {
        a[j] += __shfl_xor(a[j], 16);
        a[j] += __shfl_xor(a[j], 32);
    }
    l += __shfl_xor(l, 16);
    l += __shfl_xor(l, 32);

    const float inv = (l > 0.f) ? 1.f / l : 0.f;

    if (eg == 0) {
        const h8 ss = *reinterpret_cast<const h8*>(Sh + (size_t)node * 128 + li * 8);
        h8 ho;
#pragma unroll
        for (int j = 0; j < 4; ++j) {
            const float2 sf = __half22float2(ss.h[j]);
            const float h0 = fast_tanh(a[2 * j] * inv + sf.x);
            const float h1 = fast_tanh(a[2 * j + 1] * inv + sf.y);
            ho.h[j] = __floats2half2_rn(h0, h1);
        }
        *reinterpret_cast<h8*>(hbuf + (size_t)node * 128 + li * 8) = ho;
    }
}

// ---------------------------------------------------------------------------
// Kernel 4: readout MLP, one thread per node, weights staged in LDS.
// ---------------------------------------------------------------------------
__global__ __launch_bounds__(256) void mlp_kernel(
    const __half* __restrict__ hbuf,
    const float* __restrict__ W1, const float* __restrict__ b1,
    const float* __restrict__ W2, const float* __restrict__ b2,
    const float* __restrict__ W3, const float* __restrict__ b3,
    float* __restrict__ out)
{
    __shared__ float W1s[128][24];   // [k][j]
    __shared__ float W2s[24][8];
    __shared__ float W3s[8][2];
    __shared__ float b1s[24], b2s[8], b3s[2];

    const int tid = threadIdx.x;

    {
        const float4* src = reinterpret_cast<const float4*>(W1 + tid * 12);
        float4* dst = reinterpret_cast<float4*>(&W1s[0][0] + tid * 12);
        dst[0] = src[0];
        dst[1] = src[1];
        dst[2] = src[2];
        if (tid < 48)
            reinterpret_cast<float4*>(&W2s[0][0])[tid] =
                reinterpret_cast<const float4*>(W2)[tid];
        if (tid < 4)
            reinterpret_cast<float4*>(&W3s[0][0])[tid] =
                reinterpret_cast<const float4*>(W3)[tid];
        if (tid < 24) b1s[tid] = b1[tid];
        if (tid < 8)  b2s[tid] = b2[tid];
        if (tid < 2)  b3s[tid] = b3[tid];
    }
    __syncthreads();

    const int node = blockIdx.x * 256 + tid;
    if (node >= NN) return;

    float t24[24];
#pragma unroll
    for (int j = 0; j < 24; ++j) t24[j] = b1s[j];

    const h8* hrow = reinterpret_cast<const h8*>(hbuf + (size_t)node * 128);
#pragma unroll
    for (int c = 0; c < 16; ++c) {
        const h8 hh = hrow[c];
        float hf[8];
#pragma unroll
        for (int j = 0; j < 4; ++j) {
            const float2 f = __half22float2(hh.h[j]);
            hf[2 * j] = f.x;
            hf[2 * j + 1] = f.y;
        }
#pragma unroll
        for (int i = 0; i < 8; ++i) {
            const int kk = c * 8 + i;
#pragma unroll
            for (int j4 = 0; j4 < 6; ++j4) {
                const float4 w4 = *reinterpret_cast<const float4*>(&W1s[kk][j4 * 4]);
                t24[j4 * 4 + 0] = fmaf(hf[i], w4.x, t24[j4 * 4 + 0]);
                t24[j4 * 4 + 1] = fmaf(hf[i], w4.y, t24[j4 * 4 + 1]);
                t24[j4 * 4 + 2] = fmaf(hf[i], w4.z, t24[j4 * 4 + 2]);
                t24[j4 * 4 + 3] = fmaf(hf[i], w4.w, t24[j4 * 4 + 3]);
            }
        }
    }

    float u8[8];
#pragma unroll
    for (int j = 0; j < 8; ++j) u8[j] = b2s[j];
#pragma unroll
    for (int kk = 0; kk < 24; ++kk) {
        const float hv = t24[kk] - fast_tanh(t24[kk]);
#pragma unroll
        for (int j = 0; j < 8; ++j) u8[j] = fmaf(hv, W2s[kk][j], u8[j]);
    }

    float o0 = b3s[0], o1 = b3s[1];
#pragma unroll
    for (int kk = 0; kk < 8; ++kk) {
        const float hv = u8[kk] - fast_tanh(u8[kk]);
        o0 = fmaf(hv, W3s[kk][0], o0);
        o1 = fmaf(hv, W3s[kk][1], o1);
    }
    *reinterpret_cast<float2*>(out + (size_t)node * 2) = make_float2(o0, o1);
}

// ---------------------------------------------------------------------------
extern "C" void kernel_launch(void* const* d_in, const int* in_sizes, int n_in,
                              void* d_out, int out_size, void* d_ws, size_t ws_size,
                              hipStream_t stream)
{
    const float* x  = (const float*)d_in[0];
    const int*   ei = (const int*)d_in[1];
    const float* Wq = (const float*)d_in[2];
    const float* bq = (const float*)d_in[3];
    const float* Wk = (const float*)d_in[4];
    const float* bk = (const float*)d_in[5];
    const float* Wv = (const float*)d_in[6];
    const float* bv = (const float*)d_in[7];
    const float* Ws = (const float*)d_in[8];
    const float* bs = (const float*)d_in[9];
    const float* W1 = (const float*)d_in[10];
    const float* b1 = (const float*)d_in[11];
    const float* W2 = (const float*)d_in[12];
    const float* b2 = (const float*)d_in[13];
    const float* W3 = (const float*)d_in[14];
    const float* b3 = (const float*)d_in[15];
    float* out = (float*)d_out;

    __half* ws = (__half*)d_ws;
    __half* Qh = ws;
    __half* Sh = Qh + (size_t)NN * HD_;
    __half* KV = Sh + (size_t)NN * HD_;
    __half* hbuf = KV + (size_t)NN * 256;
    __half* Wt = hbuf + (size_t)NN * HD_;
    int* cnt  = (int*)(Wt + 65536);
    int* ssrc = cnt + NN;

    (void)hipMemsetAsync(cnt, 0, NN * sizeof(int), stream);

    wt_kernel<<<32, 256, 0, stream>>>(Wq, Wk, Wv, Ws, Wt);
    bucket_scatter<<<SCATB, 256, 0, stream>>>(ei, cnt, ssrc);
    proj_mfma<<<NN / 32, 512, 0, stream>>>(x, Wt, bq, bk, bv, bs, Qh, Sh, KV);
    attn_kernel<<<NN / 4, 256, 0, stream>>>(Qh, KV, Sh, cnt, ssrc, hbuf);
    mlp_kernel<<<(NN + 255) / 256, 256, 0, stream>>>(hbuf, W1, b1, W2, b2,
                                                     W3, b3, out);
}

// Round 14
// 254.507 us; speedup vs baseline: 1.1265x; 1.1265x over previous
//
#include <hip/hip_runtime.h>
#include <hip/hip_bf16.h>
#include <hip/hip_fp16.h>
#include <math.h>

#define NN 100000
#define EE 1600000
#define HD_ 128   // heads*hid = 4*32
#define PART 8            // dst-range groups (XCD count)
#define RNG 12500         // NN / PART
#define PBLK 128          // blocks per group (round-11 known-good)
#define SCATB (PART * PBLK)          // 1024 scatter blocks
#define PSTRIDE (PBLK * 256)
#define CAP 64            // bucket capacity per node (max deg ~42 whp)
#define PROJ_GRID 512     // weights-stationary proj blocks
#define NTILES (NN / 16)  // 6250

typedef float f32x4 __attribute__((ext_vector_type(4)));
typedef _Float16 f16x8 __attribute__((ext_vector_type(8)));
typedef _Float16 f16x2 __attribute__((ext_vector_type(2)));
typedef float accf4 __attribute__((ext_vector_type(4)));

// ---------------------------------------------------------------------------
// fast tanh via hardware exp, overflow-safe form
// ---------------------------------------------------------------------------
__device__ __forceinline__ float fast_tanh(float z) {
    float az = fabsf(z);
    float e = __expf(-2.f * az);
    float t = (1.f - e) / (1.f + e);
    return copysignf(t, z);
}

struct alignas(16) h8 { __half2 h[4]; };  // 8 halves = 16B
struct alignas(8)  h4 { __half2 a, b; };  // 4 halves = 8B

// ---------------------------------------------------------------------------
// Kernel 0: one-time W transpose/convert into MFMA A-fragment layout (fp16).
// Frag index: (((mat*8 + ct)*4 + kt)*64 + lane)*8 + j
//   element = W_mat[kt*32 + (lane>>4)*8 + j][ct*16 + (lane&15)]
// ---------------------------------------------------------------------------
__global__ __launch_bounds__(256) void wt_kernel(
    const float* __restrict__ Wq, const float* __restrict__ Wk,
    const float* __restrict__ Wv, const float* __restrict__ Ws,
    __half* __restrict__ Wt)
{
    const int t = blockIdx.x * 256 + threadIdx.x;   // 0..8191
    const int lane = t & 63;
    const int kt = (t >> 6) & 3;
    const int ct = (t >> 8) & 7;
    const int mat = t >> 11;
    const float* Wm = (mat == 0) ? Wq : (mat == 1) ? Wk : (mat == 2) ? Wv : Ws;
    const int col = ct * 16 + (lane & 15);
    const int k0 = kt * 32 + (lane >> 4) * 8;
    h8 hh;
#pragma unroll
    for (int j = 0; j < 4; ++j) {
        hh.h[j] = __floats2half2_rn(Wm[(size_t)(k0 + 2 * j) * 128 + col],
                                    Wm[(size_t)(k0 + 2 * j + 1) * 128 + col]);
    }
    *reinterpret_cast<h8*>(Wt + (size_t)t * 8) = hh;
}

// ---------------------------------------------------------------------------
// Kernel 1: weights-stationary MFMA projections.
// Block = 256 = 4 waves; wave w owns matrix w and holds its 32 W-fragments
// in registers (loaded ONCE; statically indexed via full unroll). Grid-stride
// over 16-node tiles; next tile's x loads are issued before the MFMAs so HBM
// latency hides under compute.
// ---------------------------------------------------------------------------
__global__ __launch_bounds__(256) void proj_mfma(
    const float* __restrict__ x, const __half* __restrict__ Wt,
    const float* __restrict__ bq, const float* __restrict__ bk,
    const float* __restrict__ bv, const float* __restrict__ bs,
    __half* __restrict__ Qh, __half* __restrict__ Sh, __half* __restrict__ KV)
{
    __shared__ __half xs[16][136];   // x tile fp16, padded stride
    __shared__ __half ys[16][520];   // output staging [node][mat*128+col]
    const int tid = threadIdx.x;
    const int w = tid >> 6;          // matrix
    const int lane = tid & 63;

    // ---- load this wave's 32 W-fragments into registers (once) ----
    f16x8 wf[32];
    {
        const __half* wbase = Wt + (size_t)w * 16384;
#pragma unroll
        for (int i = 0; i < 32; ++i)
            wf[i] = *reinterpret_cast<const f16x8*>(
                wbase + (size_t)(i * 64 + lane) * 8);
    }

    const float* bm = (w == 0) ? bq : (w == 1) ? bk : (w == 2) ? bv : bs;
    const float sc = (w == 0) ? 0.17677669529663687f : 1.f;  // 1/sqrt(32)

    // staging-thread roles for x tile
    const int srow = tid & 15;
    const int sk0 = (tid >> 4) * 8;

    // prologue: load first tile into regs
    int t = blockIdx.x;
    f32x4 ra, rb;
    if (t < NTILES) {
        const f32x4* xp = reinterpret_cast<const f32x4*>(
            x + (size_t)(t * 16 + srow) * 128 + sk0);
        ra = __builtin_nontemporal_load(xp);
        rb = __builtin_nontemporal_load(xp + 1);
    }

    for (; t < NTILES; t += PROJ_GRID) {
        const int n0 = t * 16;

        // write staged regs -> xs
        {
            h8 hh;
            hh.h[0] = __floats2half2_rn(ra.x, ra.y);
            hh.h[1] = __floats2half2_rn(ra.z, ra.w);
            hh.h[2] = __floats2half2_rn(rb.x, rb.y);
            hh.h[3] = __floats2half2_rn(rb.z, rb.w);
            *reinterpret_cast<h8*>(&xs[srow][sk0]) = hh;
        }
        __syncthreads();

        // issue next tile's loads (in flight during MFMAs)
        if (t + PROJ_GRID < NTILES) {
            const f32x4* xp = reinterpret_cast<const f32x4*>(
                x + (size_t)((t + PROJ_GRID) * 16 + srow) * 128 + sk0);
            ra = __builtin_nontemporal_load(xp);
            rb = __builtin_nontemporal_load(xp + 1);
        }

        // compute
        f16x8 bx[4];
#pragma unroll
        for (int kt = 0; kt < 4; ++kt)
            bx[kt] = *reinterpret_cast<const f16x8*>(
                &xs[lane & 15][kt * 32 + (lane >> 4) * 8]);

#pragma unroll
        for (int ct = 0; ct < 8; ++ct) {
            accf4 acc = {0.f, 0.f, 0.f, 0.f};
#pragma unroll
            for (int kt = 0; kt < 4; ++kt)
                acc = __builtin_amdgcn_mfma_f32_16x16x32_f16(
                    wf[ct * 4 + kt], bx[kt], acc, 0, 0, 0);
            const float4 bb = *reinterpret_cast<const float4*>(
                bm + ct * 16 + ((lane >> 4) << 2));
            h4 o;
            o.a = __floats2half2_rn((acc[0] + bb.x) * sc, (acc[1] + bb.y) * sc);
            o.b = __floats2half2_rn((acc[2] + bb.z) * sc, (acc[3] + bb.w) * sc);
            *reinterpret_cast<h4*>(
                &ys[lane & 15][w * 128 + ct * 16 + ((lane >> 4) << 2)]) = o;
        }
        __syncthreads();

        // write out contiguous fp16 rows
        {
            const int node = tid >> 4;
            const int c8 = (tid & 15) * 8;
            h8 q = *reinterpret_cast<h8*>(&ys[node][c8]);
            h8 k = *reinterpret_cast<h8*>(&ys[node][128 + c8]);
            h8 v = *reinterpret_cast<h8*>(&ys[node][256 + c8]);
            h8 s = *reinterpret_cast<h8*>(&ys[node][384 + c8]);
            *reinterpret_cast<h8*>(Qh + (size_t)(n0 + node) * 128 + c8) = q;
            *reinterpret_cast<h8*>(KV + (size_t)(n0 + node) * 256 + c8) = k;
            *reinterpret_cast<h8*>(KV + (size_t)(n0 + node) * 256 + 128 + c8) = v;
            *reinterpret_cast<h8*>(Sh + (size_t)(n0 + node) * 128 + c8) = s;
        }
        // no third sync needed: next iteration's xs writes are fenced by
        // the sync after them; ys reads above complete before that sync.
        __syncthreads();
    }
}

// ---------------------------------------------------------------------------
// Kernel 2: single-pass bucket scatter. 8-way dst-range partition (each cnt
// line and node bucket written by one XCD group).
// ---------------------------------------------------------------------------
__global__ __launch_bounds__(256) void bucket_scatter(
    const int* __restrict__ ei, int* __restrict__ cnt, int* __restrict__ ssrc)
{
    const int g = blockIdx.x & (PART - 1);
    const int bg = blockIdx.x >> 3;
    const int lo = g * RNG;
    const int hi = lo + RNG;
    for (int e = bg * 256 + threadIdx.x; e < EE; e += PSTRIDE) {
        const int d = ei[EE + e];
        if (d >= lo && d < hi) {
            int pos = atomicAdd(&cnt[d], 1);
            if (pos < CAP) ssrc[(d << 6) | pos] = ei[e];
        }
    }
}

// ---------------------------------------------------------------------------
// Kernel 3: per-node attention (no-max softmax) + skip + tanh -> h (fp16).
// One wave per node, NO LDS. 16 edges/iteration in four 4-edge batches.
// ---------------------------------------------------------------------------
__global__ __launch_bounds__(256) void attn_kernel(
    const __half* __restrict__ Qh, const __half* __restrict__ KV,
    const __half* __restrict__ Sh,
    const int* __restrict__ cnt, const int* __restrict__ ssrc,
    __half* __restrict__ hbuf)
{
    const int wid = threadIdx.x >> 6;
    const int lane = threadIdx.x & 63;
    const int node = blockIdx.x * 4 + wid;
    const int eg = lane >> 4;   // edge slot
    const int li = lane & 15;   // position within row

    // q dims 8*li..8*li+7, kept packed fp16 (pre-scaled by 1/sqrt(32))
    h8 qq = *reinterpret_cast<const h8*>(Qh + (size_t)node * 128 + li * 8);
    f16x2 qp[4];
#pragma unroll
    for (int j = 0; j < 4; ++j)
        qp[j] = *reinterpret_cast<const f16x2*>(&qq.h[j]);

    float a[8];
#pragma unroll
    for (int j = 0; j < 8; ++j) a[j] = 0.f;
    float l = 0.f;

    const int st = node << 6;
    int dg = cnt[node];
    if (dg > CAP) dg = CAP;

    for (int it = 0; it < dg; it += 16) {
        const __half* rows[4];
        bool val[4];
#pragma unroll
        for (int b = 0; b < 4; ++b) {
            const int e = it + b * 4 + eg;
            val[b] = e < dg;
            const int src = ssrc[st + (val[b] ? e : 0)];
            rows[b] = KV + (size_t)src * 256 + li * 8;
        }

        h8 kk[4], vv[4];
#pragma unroll
        for (int b = 0; b < 4; ++b) {
            kk[b] = *reinterpret_cast<const h8*>(rows[b]);
            vv[b] = *reinterpret_cast<const h8*>(rows[b] + 128);
        }

        float p[4];
#pragma unroll
        for (int b = 0; b < 4; ++b) {
            float s = 0.f;
#if __has_builtin(__builtin_amdgcn_fdot2)
#pragma unroll
            for (int j = 0; j < 4; ++j)
                s = __builtin_amdgcn_fdot2(
                        qp[j], *reinterpret_cast<const f16x2*>(&kk[b].h[j]),
                        s, false);
#else
#pragma unroll
            for (int j = 0; j < 4; ++j) {
                const float2 kf = __half22float2(kk[b].h[j]);
                const float2 qf = __half22float2(qq.h[j]);
                s = fmaf(qf.x, kf.x, s);
                s = fmaf(qf.y, kf.y, s);
            }
#endif
            p[b] = s;
        }

#pragma unroll
        for (int b = 0; b < 4; ++b) {
            p[b] += __shfl_xor(p[b], 1);
            p[b] += __shfl_xor(p[b], 2);
        }

        float w[4];
#pragma unroll
        for (int b = 0; b < 4; ++b) {
            w[b] = val[b] ? __expf(p[b]) : 0.f;
            l += w[b];
        }

#pragma unroll
        for (int b = 0; b < 4; ++b) {
#pragma unroll
            for (int j = 0; j < 4; ++j) {
                const float2 vf = __half22float2(vv[b].h[j]);
                a[2 * j]     = fmaf(w[b], vf.x, a[2 * j]);
                a[2 * j + 1] = fmaf(w[b], vf.y, a[2 * j + 1]);
            }
        }
    }

    // combine the 4 edge slots
#pragma unroll
    for (int j = 0; j < 8; ++j) {
        a[j] += __shfl_xor(a[j], 16);
        a[j] += __shfl_xor(a[j], 32);
    }
    l += __shfl_xor(l, 16);
    l += __shfl_xor(l, 32);

    const float inv = (l > 0.f) ? 1.f / l : 0.f;

    if (eg == 0) {
        const h8 ss = *reinterpret_cast<const h8*>(Sh + (size_t)node * 128 + li * 8);
        h8 ho;
#pragma unroll
        for (int j = 0; j < 4; ++j) {
            const float2 sf = __half22float2(ss.h[j]);
            const float h0 = fast_tanh(a[2 * j] * inv + sf.x);
            const float h1 = fast_tanh(a[2 * j + 1] * inv + sf.y);
            ho.h[j] = __floats2half2_rn(h0, h1);
        }
        *reinterpret_cast<h8*>(hbuf + (size_t)node * 128 + li * 8) = ho;
    }
}

// ---------------------------------------------------------------------------
// Kernel 4: readout MLP, one thread per node, weights staged in LDS.
// ---------------------------------------------------------------------------
__global__ __launch_bounds__(256) void mlp_kernel(
    const __half* __restrict__ hbuf,
    const float* __restrict__ W1, const float* __restrict__ b1,
    const float* __restrict__ W2, const float* __restrict__ b2,
    const float* __restrict__ W3, const float* __restrict__ b3,
    float* __restrict__ out)
{
    __shared__ float W1s[128][24];   // [k][j]
    __shared__ float W2s[24][8];
    __shared__ float W3s[8][2];
    __shared__ float b1s[24], b2s[8], b3s[2];

    const int tid = threadIdx.x;

    {
        const float4* src = reinterpret_cast<const float4*>(W1 + tid * 12);
        float4* dst = reinterpret_cast<float4*>(&W1s[0][0] + tid * 12);
        dst[0] = src[0];
        dst[1] = src[1];
        dst[2] = src[2];
        if (tid < 48)
            reinterpret_cast<float4*>(&W2s[0][0])[tid] =
                reinterpret_cast<const float4*>(W2)[tid];
        if (tid < 4)
            reinterpret_cast<float4*>(&W3s[0][0])[tid] =
                reinterpret_cast<const float4*>(W3)[tid];
        if (tid < 24) b1s[tid] = b1[tid];
        if (tid < 8)  b2s[tid] = b2[tid];
        if (tid < 2)  b3s[tid] = b3[tid];
    }
    __syncthreads();

    const int node = blockIdx.x * 256 + tid;
    if (node >= NN) return;

    float t24[24];
#pragma unroll
    for (int j = 0; j < 24; ++j) t24[j] = b1s[j];

    const h8* hrow = reinterpret_cast<const h8*>(hbuf + (size_t)node * 128);
#pragma unroll
    for (int c = 0; c < 16; ++c) {
        const h8 hh = hrow[c];
        float hf[8];
#pragma unroll
        for (int j = 0; j < 4; ++j) {
            const float2 f = __half22float2(hh.h[j]);
            hf[2 * j] = f.x;
            hf[2 * j + 1] = f.y;
        }
#pragma unroll
        for (int i = 0; i < 8; ++i) {
            const int kk = c * 8 + i;
#pragma unroll
            for (int j4 = 0; j4 < 6; ++j4) {
                const float4 w4 = *reinterpret_cast<const float4*>(&W1s[kk][j4 * 4]);
                t24[j4 * 4 + 0] = fmaf(hf[i], w4.x, t24[j4 * 4 + 0]);
                t24[j4 * 4 + 1] = fmaf(hf[i], w4.y, t24[j4 * 4 + 1]);
                t24[j4 * 4 + 2] = fmaf(hf[i], w4.z, t24[j4 * 4 + 2]);
                t24[j4 * 4 + 3] = fmaf(hf[i], w4.w, t24[j4 * 4 + 3]);
            }
        }
    }

    float u8[8];
#pragma unroll
    for (int j = 0; j < 8; ++j) u8[j] = b2s[j];
#pragma unroll
    for (int kk = 0; kk < 24; ++kk) {
        const float hv = t24[kk] - fast_tanh(t24[kk]);
#pragma unroll
        for (int j = 0; j < 8; ++j) u8[j] = fmaf(hv, W2s[kk][j], u8[j]);
    }

    float o0 = b3s[0], o1 = b3s[1];
#pragma unroll
    for (int kk = 0; kk < 8; ++kk) {
        const float hv = u8[kk] - fast_tanh(u8[kk]);
        o0 = fmaf(hv, W3s[kk][0], o0);
        o1 = fmaf(hv, W3s[kk][1], o1);
    }
    *reinterpret_cast<float2*>(out + (size_t)node * 2) = make_float2(o0, o1);
}

// ---------------------------------------------------------------------------
extern "C" void kernel_launch(void* const* d_in, const int* in_sizes, int n_in,
                              void* d_out, int out_size, void* d_ws, size_t ws_size,
                              hipStream_t stream)
{
    const float* x  = (const float*)d_in[0];
    const int*   ei = (const int*)d_in[1];
    const float* Wq = (const float*)d_in[2];
    const float* bq = (const float*)d_in[3];
    const float* Wk = (const float*)d_in[4];
    const float* bk = (const float*)d_in[5];
    const float* Wv = (const float*)d_in[6];
    const float* bv = (const float*)d_in[7];
    const float* Ws = (const float*)d_in[8];
    const float* bs = (const float*)d_in[9];
    const float* W1 = (const float*)d_in[10];
    const float* b1 = (const float*)d_in[11];
    const float* W2 = (const float*)d_in[12];
    const float* b2 = (const float*)d_in[13];
    const float* W3 = (const float*)d_in[14];
    const float* b3 = (const float*)d_in[15];
    float* out = (float*)d_out;

    __half* ws = (__half*)d_ws;
    __half* Qh = ws;
    __half* Sh = Qh + (size_t)NN * HD_;
    __half* KV = Sh + (size_t)NN * HD_;
    __half* hbuf = KV + (size_t)NN * 256;
    __half* Wt = hbuf + (size_t)NN * HD_;
    int* cnt  = (int*)(Wt + 65536);
    int* ssrc = cnt + NN;

    (void)hipMemsetAsync(cnt, 0, NN * sizeof(int), stream);

    wt_kernel<<<32, 256, 0, stream>>>(Wq, Wk, Wv, Ws, Wt);
    bucket_scatter<<<SCATB, 256, 0, stream>>>(ei, cnt, ssrc);
    proj_mfma<<<PROJ_GRID, 256, 0, stream>>>(x, Wt, bq, bk, bv, bs, Qh, Sh, KV);
    attn_kernel<<<NN / 4, 256, 0, stream>>>(Qh, KV, Sh, cnt, ssrc, hbuf);
    mlp_kernel<<<(NN + 255) / 256, 256, 0, stream>>>(hbuf, W1, b1, W2, b2,
                                                     W3, b3, out);
}